// Round 10
// baseline (169.241 us; speedup 1.0000x reference)
//
#include <hip/hip_runtime.h>

// ROI bilinear pooling (TF1 resize_images align_corners=False semantics).
// img: (1, 100, 100, 1024) f32 NHWC ; rois: (1, 512, 4) f32 (int-valued x,y,w,h)
// out: (1, 512, 7, 7, 1024) f32
//
// v2b: 2048 persistent blocks (8/CU, 32 waves/CU), contiguous chunk of ~12-13
// output positions per block, 2-deep software pipeline (8 loads in flight),
// XCD-chunked block swizzle (64 consecutive ROIs per XCD L2), nontemporal
// stores for the streaming 100 MB output. (v2b: native clang vector type for
// __builtin_nontemporal_store — HIP_vector_type float4 is rejected.)

#define IMG_H 100
#define IMG_W 100
#define IMG_C 1024
#define N_ROI 512
#define POOLP 7
#define NPOS  (N_ROI * POOLP * POOLP)   // 25088
#define NBLK  2048                       // 8 blocks/CU exactly

typedef float f32x4 __attribute__((ext_vector_type(4)));

__device__ __forceinline__ void pos_setup(
    const float* __restrict__ img, const float* __restrict__ rois,
    int p, int c,
    const f32x4*& q00, const f32x4*& q01, const f32x4*& q10, const f32x4*& q11,
    float& fx, float& fy)
{
    const int roi = p / 49;
    const int pos = p - roi * 49;
    const int py  = pos / 7;
    const int px  = pos - py * 7;

    const f32x4 rv = *reinterpret_cast<const f32x4*>(rois + roi * 4);
    const int x = (int)rv.x;
    const int y = (int)rv.y;
    const int w = (int)rv.z;
    const int h = (int)rv.w;

    // keep EXACT reference math: s = out_idx * (size / 7.0f), floor
    const float sx  = (float)px * ((float)w / (float)POOLP);
    const int   ix0 = (int)floorf(sx);
    const int   ix1 = min(ix0 + 1, w - 1);
    fx = sx - (float)ix0;
    const int ax0 = min(max(x + ix0, 0), IMG_W - 1);
    const int ax1 = min(max(x + ix1, 0), IMG_W - 1);

    const float sy  = (float)py * ((float)h / (float)POOLP);
    const int   iy0 = (int)floorf(sy);
    const int   iy1 = min(iy0 + 1, h - 1);
    fy = sy - (float)iy0;
    const int ay0 = min(max(y + iy0, 0), IMG_H - 1);
    const int ay1 = min(max(y + iy1, 0), IMG_H - 1);

    q00 = reinterpret_cast<const f32x4*>(img + ((size_t)(ay0 * IMG_W + ax0) * IMG_C + c));
    q01 = reinterpret_cast<const f32x4*>(img + ((size_t)(ay0 * IMG_W + ax1) * IMG_C + c));
    q10 = reinterpret_cast<const f32x4*>(img + ((size_t)(ay1 * IMG_W + ax0) * IMG_C + c));
    q11 = reinterpret_cast<const f32x4*>(img + ((size_t)(ay1 * IMG_W + ax1) * IMG_C + c));
}

__device__ __forceinline__ f32x4 blend(
    f32x4 v00, f32x4 v01, f32x4 v10, f32x4 v11, float fx, float fy)
{
    const float gx = 1.0f - fx;
    const float gy = 1.0f - fy;
    f32x4 top = v00 * gx + v01 * fx;
    f32x4 bot = v10 * gx + v11 * fx;
    return top * gy + bot * fy;
}

__global__ __launch_bounds__(256) void roi_pool_kernel(
    const float* __restrict__ img,
    const float* __restrict__ rois,
    float* __restrict__ out)
{
    const int b = blockIdx.x;
    // XCD-chunked swizzle: XCD (b & 7) gets a contiguous chunk-id range ->
    // contiguous position range -> 64 consecutive ROIs per XCD L2.
    const int cid = ((b & 7) << 8) | (b >> 3);        // NBLK/8 == 256
    const int p0  = (int)(((long long)cid       * NPOS) / NBLK);
    const int p1  = (int)(((long long)(cid + 1) * NPOS) / NBLK);
    if (p0 >= p1) return;

    const int c = threadIdx.x << 2;   // 4 channels per thread

    const f32x4 *q00, *q01, *q10, *q11;
    float fx, fy;
    pos_setup(img, rois, p0, c, q00, q01, q10, q11, fx, fy);
    f32x4 v00 = *q00;
    f32x4 v01 = *q01;
    f32x4 v10 = *q10;
    f32x4 v11 = *q11;

    for (int p = p0 + 1; p < p1; ++p) {
        // issue next position's loads before consuming current (2-deep pipeline)
        const f32x4 *r00, *r01, *r10, *r11;
        float nfx, nfy;
        pos_setup(img, rois, p, c, r00, r01, r10, r11, nfx, nfy);
        f32x4 w00 = *r00;
        f32x4 w01 = *r01;
        f32x4 w10 = *r10;
        f32x4 w11 = *r11;

        const f32x4 o = blend(v00, v01, v10, v11, fx, fy);
        __builtin_nontemporal_store(
            o, reinterpret_cast<f32x4*>(out + (size_t)(p - 1) * IMG_C + c));

        v00 = w00; v01 = w01; v10 = w10; v11 = w11;
        fx = nfx; fy = nfy;
    }

    const f32x4 o = blend(v00, v01, v10, v11, fx, fy);
    __builtin_nontemporal_store(
        o, reinterpret_cast<f32x4*>(out + (size_t)(p1 - 1) * IMG_C + c));
}

extern "C" void kernel_launch(void* const* d_in, const int* in_sizes, int n_in,
                              void* d_out, int out_size, void* d_ws, size_t ws_size,
                              hipStream_t stream)
{
    const float* img  = (const float*)d_in[0];
    const float* rois = (const float*)d_in[1];
    float* out = (float*)d_out;

    roi_pool_kernel<<<NBLK, 256, 0, stream>>>(img, rois, out);
}

// Round 12
// 161.721 us; speedup vs baseline: 1.0465x; 1.0465x over previous
//
#include <hip/hip_runtime.h>

// ROI bilinear pooling (TF1 resize_images align_corners=False semantics).
// img: (1, 100, 100, 1024) f32 NHWC ; rois: (1, 512, 4) f32 (int-valued x,y,w,h)
// out: (1, 512, 7, 7, 1024) f32
//
// v3: XCD-local ROI-major sweep. XCD (b&7) owns 64 consecutive ROIs (3136
// position-units). Its 256 blocks walk those units with stride 256, so the
// XCD's in-flight positions span only ~5 consecutive ROIs at any instant
// (~15 MB footprint vs 41 MB whole image) -> higher L2 hit rate -> less
// L2-miss (TCC FETCH) traffic on the L2<->L3/IF path, which round-10
// counters implicate as the bottleneck (time invariant to HBM bytes,
// L2-miss BW pinned at ~3.6-4.1 TB/s in both prior variants).
// Keeps v2b's 2-deep pipeline and nontemporal stores.

#define IMG_H 100
#define IMG_W 100
#define IMG_C 1024
#define N_ROI 512
#define POOLP 7
#define NPOS  (N_ROI * POOLP * POOLP)   // 25088
#define NBLK  2048                       // 8 blocks/CU exactly
#define ROI_PER_XCD   (N_ROI / 8)        // 64
#define UNITS_PER_XCD (ROI_PER_XCD * 49) // 3136
#define BLK_PER_XCD   (NBLK / 8)         // 256

typedef float f32x4 __attribute__((ext_vector_type(4)));

__device__ __forceinline__ void pos_setup(
    const float* __restrict__ img, const float* __restrict__ rois,
    int p, int c,
    const f32x4*& q00, const f32x4*& q01, const f32x4*& q10, const f32x4*& q11,
    float& fx, float& fy)
{
    const int roi = p / 49;
    const int pos = p - roi * 49;
    const int py  = pos / 7;
    const int px  = pos - py * 7;

    const f32x4 rv = *reinterpret_cast<const f32x4*>(rois + roi * 4);
    const int x = (int)rv.x;
    const int y = (int)rv.y;
    const int w = (int)rv.z;
    const int h = (int)rv.w;

    // keep EXACT reference math: s = out_idx * (size / 7.0f), floor
    const float sx  = (float)px * ((float)w / (float)POOLP);
    const int   ix0 = (int)floorf(sx);
    const int   ix1 = min(ix0 + 1, w - 1);
    fx = sx - (float)ix0;
    const int ax0 = min(max(x + ix0, 0), IMG_W - 1);
    const int ax1 = min(max(x + ix1, 0), IMG_W - 1);

    const float sy  = (float)py * ((float)h / (float)POOLP);
    const int   iy0 = (int)floorf(sy);
    const int   iy1 = min(iy0 + 1, h - 1);
    fy = sy - (float)iy0;
    const int ay0 = min(max(y + iy0, 0), IMG_H - 1);
    const int ay1 = min(max(y + iy1, 0), IMG_H - 1);

    q00 = reinterpret_cast<const f32x4*>(img + ((size_t)(ay0 * IMG_W + ax0) * IMG_C + c));
    q01 = reinterpret_cast<const f32x4*>(img + ((size_t)(ay0 * IMG_W + ax1) * IMG_C + c));
    q10 = reinterpret_cast<const f32x4*>(img + ((size_t)(ay1 * IMG_W + ax0) * IMG_C + c));
    q11 = reinterpret_cast<const f32x4*>(img + ((size_t)(ay1 * IMG_W + ax1) * IMG_C + c));
}

__device__ __forceinline__ f32x4 blend(
    f32x4 v00, f32x4 v01, f32x4 v10, f32x4 v11, float fx, float fy)
{
    const float gx = 1.0f - fx;
    const float gy = 1.0f - fy;
    f32x4 top = v00 * gx + v01 * fx;
    f32x4 bot = v10 * gx + v11 * fx;
    return top * gy + bot * fy;
}

__global__ __launch_bounds__(256) void roi_pool_kernel(
    const float* __restrict__ img,
    const float* __restrict__ rois,
    float* __restrict__ out)
{
    const int b    = blockIdx.x;
    const int xcd  = b & 7;           // heuristic XCD id (round-robin dispatch)
    const int l    = b >> 3;          // local block on this XCD, 0..255
    const int base = xcd * UNITS_PER_XCD;

    const int c = threadIdx.x << 2;   // 4 channels per thread

    int u = l;                        // position-unit within this XCD's range
    // prologue: load position base+u
    const f32x4 *q00, *q01, *q10, *q11;
    float fx, fy;
    pos_setup(img, rois, base + u, c, q00, q01, q10, q11, fx, fy);
    f32x4 v00 = *q00;
    f32x4 v01 = *q01;
    f32x4 v10 = *q10;
    f32x4 v11 = *q11;

    for (int un = u + BLK_PER_XCD; un < UNITS_PER_XCD; un += BLK_PER_XCD) {
        // issue next unit's loads before consuming current (2-deep pipeline)
        const f32x4 *r00, *r01, *r10, *r11;
        float nfx, nfy;
        pos_setup(img, rois, base + un, c, r00, r01, r10, r11, nfx, nfy);
        f32x4 w00 = *r00;
        f32x4 w01 = *r01;
        f32x4 w10 = *r10;
        f32x4 w11 = *r11;

        const f32x4 o = blend(v00, v01, v10, v11, fx, fy);
        __builtin_nontemporal_store(
            o, reinterpret_cast<f32x4*>(out + (size_t)(base + u) * IMG_C + c));

        v00 = w00; v01 = w01; v10 = w10; v11 = w11;
        fx = nfx; fy = nfy;
        u = un;
    }

    const f32x4 o = blend(v00, v01, v10, v11, fx, fy);
    __builtin_nontemporal_store(
        o, reinterpret_cast<f32x4*>(out + (size_t)(base + u) * IMG_C + c));
}

extern "C" void kernel_launch(void* const* d_in, const int* in_sizes, int n_in,
                              void* d_out, int out_size, void* d_ws, size_t ws_size,
                              hipStream_t stream)
{
    const float* img  = (const float*)d_in[0];
    const float* rois = (const float*)d_in[1];
    float* out = (float*)d_out;

    roi_pool_kernel<<<NBLK, 256, 0, stream>>>(img, rois, out);
}

// Round 13
// 160.667 us; speedup vs baseline: 1.0534x; 1.0066x over previous
//
#include <hip/hip_runtime.h>

// ROI bilinear pooling (TF1 resize_images align_corners=False semantics).
// img: (1, 100, 100, 1024) f32 NHWC ; rois: (1, 512, 4) f32 (int-valued x,y,w,h)
// out: (1, 512, 7, 7, 1024) f32
//
// v4: v3's XCD-local ROI-major sweep + PAIR PROCESSING: each block handles two
// adjacent output positions per iteration -> 8 data loads per iteration, 16
// outstanding with the 2-deep pipeline (vs 8 in v3). Attacks the
// latency-bound profile (all pipes <=25% busy at ~60 us, occupancy ~51%).
// Adjacent positions share source rows -> extra loads mostly L1/L2 hits.
// Keeps nontemporal stores and 2048-block persistent geometry.

#define IMG_H 100
#define IMG_W 100
#define IMG_C 1024
#define N_ROI 512
#define POOLP 7
#define NPOS  (N_ROI * POOLP * POOLP)    // 25088
#define NBLK  2048                        // 8 blocks/CU exactly
#define ROI_PER_XCD   (N_ROI / 8)         // 64
#define UNITS_PER_XCD (ROI_PER_XCD * 49)  // 3136
#define PAIRS_PER_XCD (UNITS_PER_XCD / 2) // 1568
#define BLK_PER_XCD   (NBLK / 8)          // 256

typedef float f32x4 __attribute__((ext_vector_type(4)));

struct Stage {
    f32x4 v00, v01, v10, v11;
    float fx, fy;
};

// Issue the 4 loads for position p (channel group c). Loads are issued here;
// consumers wait via compiler-inserted waitcnt at first use.
__device__ __forceinline__ Stage load_pos(
    const float* __restrict__ img, const float* __restrict__ rois,
    int p, int c)
{
    const int roi = p / 49;
    const int pos = p - roi * 49;
    const int py  = pos / 7;
    const int px  = pos - py * 7;

    const f32x4 rv = *reinterpret_cast<const f32x4*>(rois + roi * 4);
    const int x = (int)rv.x;
    const int y = (int)rv.y;
    const int w = (int)rv.z;
    const int h = (int)rv.w;

    // keep EXACT reference math: s = out_idx * (size / 7.0f), floor
    const float sx  = (float)px * ((float)w / (float)POOLP);
    const int   ix0 = (int)floorf(sx);
    const int   ix1 = min(ix0 + 1, w - 1);
    const float fx  = sx - (float)ix0;
    const int ax0 = min(max(x + ix0, 0), IMG_W - 1);
    const int ax1 = min(max(x + ix1, 0), IMG_W - 1);

    const float sy  = (float)py * ((float)h / (float)POOLP);
    const int   iy0 = (int)floorf(sy);
    const int   iy1 = min(iy0 + 1, h - 1);
    const float fy  = sy - (float)iy0;
    const int ay0 = min(max(y + iy0, 0), IMG_H - 1);
    const int ay1 = min(max(y + iy1, 0), IMG_H - 1);

    Stage s;
    s.v00 = *reinterpret_cast<const f32x4*>(img + ((size_t)(ay0 * IMG_W + ax0) * IMG_C + c));
    s.v01 = *reinterpret_cast<const f32x4*>(img + ((size_t)(ay0 * IMG_W + ax1) * IMG_C + c));
    s.v10 = *reinterpret_cast<const f32x4*>(img + ((size_t)(ay1 * IMG_W + ax0) * IMG_C + c));
    s.v11 = *reinterpret_cast<const f32x4*>(img + ((size_t)(ay1 * IMG_W + ax1) * IMG_C + c));
    s.fx = fx;
    s.fy = fy;
    return s;
}

__device__ __forceinline__ f32x4 blend(const Stage& s)
{
    const float gx = 1.0f - s.fx;
    const float gy = 1.0f - s.fy;
    f32x4 top = s.v00 * gx + s.v01 * s.fx;
    f32x4 bot = s.v10 * gx + s.v11 * s.fx;
    return top * gy + bot * gy + (bot - bot) * 0.0f;  // placeholder; fixed below
}

// NOTE: blend above intentionally replaced by correct inline code in kernel
// (kept simple to avoid any chance of algebraic drift).

__global__ __launch_bounds__(256) void roi_pool_kernel(
    const float* __restrict__ img,
    const float* __restrict__ rois,
    float* __restrict__ out)
{
    const int b    = blockIdx.x;
    const int xcd  = b & 7;           // heuristic XCD id (round-robin dispatch)
    const int l    = b >> 3;          // local block on this XCD, 0..255
    const int base = xcd * UNITS_PER_XCD;

    const int c = threadIdx.x << 2;   // 4 channels per thread

    int pu = l;                       // pair index within this XCD
    // prologue: issue loads for pair (2*pu, 2*pu+1)
    Stage sA = load_pos(img, rois, base + 2 * pu,     c);
    Stage sB = load_pos(img, rois, base + 2 * pu + 1, c);

    for (int pn = pu + BLK_PER_XCD; pn < PAIRS_PER_XCD; pn += BLK_PER_XCD) {
        // issue next pair's 8 loads before consuming current pair
        Stage nA = load_pos(img, rois, base + 2 * pn,     c);
        Stage nB = load_pos(img, rois, base + 2 * pn + 1, c);

        {
            const float gxA = 1.0f - sA.fx, gyA = 1.0f - sA.fy;
            f32x4 topA = sA.v00 * gxA + sA.v01 * sA.fx;
            f32x4 botA = sA.v10 * gxA + sA.v11 * sA.fx;
            f32x4 oA = topA * gyA + botA * sA.fy;
            __builtin_nontemporal_store(
                oA, reinterpret_cast<f32x4*>(out + (size_t)(base + 2 * pu) * IMG_C + c));

            const float gxB = 1.0f - sB.fx, gyB = 1.0f - sB.fy;
            f32x4 topB = sB.v00 * gxB + sB.v01 * sB.fx;
            f32x4 botB = sB.v10 * gxB + sB.v11 * sB.fx;
            f32x4 oB = topB * gyB + botB * sB.fy;
            __builtin_nontemporal_store(
                oB, reinterpret_cast<f32x4*>(out + (size_t)(base + 2 * pu + 1) * IMG_C + c));
        }

        sA = nA; sB = nB;
        pu = pn;
    }

    {
        const float gxA = 1.0f - sA.fx, gyA = 1.0f - sA.fy;
        f32x4 topA = sA.v00 * gxA + sA.v01 * sA.fx;
        f32x4 botA = sA.v10 * gxA + sA.v11 * sA.fx;
        f32x4 oA = topA * gyA + botA * sA.fy;
        __builtin_nontemporal_store(
            oA, reinterpret_cast<f32x4*>(out + (size_t)(base + 2 * pu) * IMG_C + c));

        const float gxB = 1.0f - sB.fx, gyB = 1.0f - sB.fy;
        f32x4 topB = sB.v00 * gxB + sB.v01 * sB.fx;
        f32x4 botB = sB.v10 * gxB + sB.v11 * sB.fx;
        f32x4 oB = topB * gyB + botB * sB.fy;
        __builtin_nontemporal_store(
            oB, reinterpret_cast<f32x4*>(out + (size_t)(base + 2 * pu + 1) * IMG_C + c));
    }
}

extern "C" void kernel_launch(void* const* d_in, const int* in_sizes, int n_in,
                              void* d_out, int out_size, void* d_ws, size_t ws_size,
                              hipStream_t stream)
{
    const float* img  = (const float*)d_in[0];
    const float* rois = (const float*)d_in[1];
    float* out = (float*)d_out;

    roi_pool_kernel<<<NBLK, 256, 0, stream>>>(img, rois, out);
}